// Round 3
// baseline (37.129 us; speedup 1.0000x reference)
//
#include <hip/hip_runtime.h>

// CASSI base-mode forward on MI355X (gfx950).
// x:  (1, 31, 1024, 1024) f32, ca: (1, 1, 1024, 1024) f32
// out: (1, 1, 1024, 1054) f32
// Gather: out[m][c] = sum_l x[l][m][c-l] * ca[m][c-l].
//
// Round-3: 4 columns/thread, 16B x-loads (dword-aligned, possibly 16B-
// misaligned -> __builtin_memcpy so codegen stays legal), ca window staged
// LDS -> 34 registers. Block = 64 threads (1 wave) covering 256 columns.
// Fast path proven in-bounds for c0 <= 1048; the single tail quad per row
// (c0 == 1052) uses a scalar bounds-checked loop.

constexpr int L = 31;
constexpr int M = 1024;
constexpr int N = 1024;
constexpr int NC = N + L - 1;            // 1054 output columns
constexpr int LSTRIDE = M * N;           // elements between successive l-slices
constexpr int BLK = 64;                  // threads per block (1 wave)
constexpr int COLS_PER_BLK = BLK * 4;    // 256 columns per block
constexpr int HALO = L - 1;              // 30
constexpr int CA_TILE = COLS_PER_BLK + HALO;  // 286 staged ca columns

typedef float f32x4 __attribute__((ext_vector_type(4)));

__global__ __launch_bounds__(BLK) void cassi_fwd_kernel(
    const float* __restrict__ x,
    const float* __restrict__ ca,
    float* __restrict__ out)
{
    __shared__ float sca[CA_TILE];

    const int tid = threadIdx.x;
    const int C0  = blockIdx.x * COLS_PER_BLK;  // first column of this block
    const int m   = blockIdx.y;                 // row

    // Stage ca[m][C0-30 .. C0+255] into LDS, zero-padding out-of-range cols.
    for (int i = tid; i < CA_TILE; i += BLK) {
        const int col = C0 - HALO + i;
        sca[i] = (col >= 0 && col < N) ? ca[m * N + col] : 0.0f;
    }
    __syncthreads();

    const int c0 = C0 + tid * 4;          // this thread's first output column
    if (c0 >= NC) return;                 // (after the barrier)

    // Hoist this thread's ca window into registers: sca[tid*4 .. tid*4+33].
    float car[34];
#pragma unroll
    for (int j = 0; j < 34; ++j) car[j] = sca[tid * 4 + j];

    if (c0 <= 1048) {
        // Fast path: 31 x 16B loads. Max offset touched:
        // l=30, m=1023, col c0+3=1051: 30*2^20 + 1023*1024 + 1021 < 31*2^20. OK.
        const float* xp = x + m * N + c0;   // tap l reads 4 floats at xp + l*LSTRIDE - l
        float acc[4] = {0.f, 0.f, 0.f, 0.f};
#pragma unroll
        for (int l = 0; l < L; ++l) {
            f32x4 q;
            __builtin_memcpy(&q, xp + (long)l * LSTRIDE - l, 16);
#pragma unroll
            for (int j = 0; j < 4; ++j)
                acc[j] = fmaf(q[j], car[j + HALO - l], acc[j]);
        }
        float* op = out + (long)m * NC + c0;
#pragma unroll
        for (int j = 0; j < 4; ++j) op[j] = acc[j];
    } else {
        // Tail quad (c0 == 1052): scalar, load only provably in-bounds taps.
        for (int j = 0; j < 4; ++j) {
            const int c = c0 + j;
            if (c >= NC) break;
            const int llo = (c > N - 1) ? (c - (N - 1)) : 0;
            float a = 0.f;
            for (int l = llo; l < L; ++l)
                a = fmaf(x[(long)l * LSTRIDE + m * N + c - l],
                         car[j + HALO - l], a);
            out[(long)m * NC + c] = a;
        }
    }
}

extern "C" void kernel_launch(void* const* d_in, const int* in_sizes, int n_in,
                              void* d_out, int out_size, void* d_ws, size_t ws_size,
                              hipStream_t stream)
{
    const float* x  = (const float*)d_in[0];
    const float* ca = (const float*)d_in[1];
    float* out = (float*)d_out;

    dim3 block(BLK, 1, 1);
    dim3 grid((NC + COLS_PER_BLK - 1) / COLS_PER_BLK, M, 1);   // (5, 1024)
    cassi_fwd_kernel<<<grid, block, 0, stream>>>(x, ca, out);
}

// Round 4
// 29.382 us; speedup vs baseline: 1.2637x; 1.2637x over previous
//
#include <hip/hip_runtime.h>

// CASSI base-mode forward on MI355X (gfx950).
// x:  (1, 31, 1024, 1024) f32, ca: (1, 1, 1024, 1024) f32
// out: (1, 1, 1024, 1054) f32
// Gather: out[m][c] = sum_l x[l][m][c-l] * ca[m][c-l].
//
// Round-4: revert round-3's misaligned dwordx4 + 64-thread blocks (regressed:
// occupancy 0.8%, VALUBusy 0.08%). Keep round-2's coalesced scalar-dword
// gather, add 4-rows-per-thread m-tiling: 124 independent loads/thread (4x
// MLP), ca staged transposed so one ds_read_b128 per tap serves all 4 rows,
// staging+barrier amortized over 4x outputs, 1280 blocks (5/CU exactly).

constexpr int L = 31;
constexpr int M = 1024;
constexpr int N = 1024;
constexpr int NC = N + L - 1;            // 1054 output columns
constexpr int LSTRIDE = M * N;           // elements between successive l-slices
constexpr int BLK = 256;                 // threads per block
constexpr int ROWS = 4;                  // output rows per block/thread
constexpr int HALO = L - 1;              // 30
constexpr int CA_TILE = BLK + HALO;      // 286 window positions

typedef float f32x4 __attribute__((ext_vector_type(4)));

__global__ __launch_bounds__(BLK) void cassi_fwd_kernel(
    const float* __restrict__ x,
    const float* __restrict__ ca,
    float* __restrict__ out)
{
    __shared__ f32x4 scaT[CA_TILE];       // [window pos][row 0..3], 4.6 KB

    const int tid = threadIdx.x;
    const int C0  = blockIdx.x * BLK;     // first output column of this block
    const int m0  = blockIdx.y * ROWS;    // first output row of this block

    // Stage ca for 4 rows, transposed: scaT[w][i] = ca[m0+i][C0-30+w],
    // zero-padded outside [0,N). Linear LDS writes, 64B-segment global reads.
    for (int idx = tid; idx < CA_TILE * ROWS; idx += BLK) {
        const int w   = idx >> 2;         // window position
        const int i   = idx & 3;          // row within tile
        const int col = C0 - HALO + w;
        float v = 0.0f;
        if (col >= 0 && col < N) v = ca[(m0 + i) * N + col];
        ((float*)scaT)[idx] = v;
    }
    __syncthreads();

    const int c = C0 + tid;               // this thread's output column
    if (c >= NC) return;                  // (after the barrier)

    // Row m0+i, tap l reads x index m0*N + c + l*LSTRIDE - l + i*N.
    // Max index (l=30, m0+i=1023, c=1053) = 31*2^20 - 1: in bounds.
    // Min index (l>=1, c<l) >= 2^20 - 30 > 0: in bounds (value * 0.0 pad).
    const float* xp = x + m0 * N + c;

    float acc[ROWS] = {0.f, 0.f, 0.f, 0.f};
#pragma unroll
    for (int l = 0; l < L; ++l) {
        const f32x4 cav = scaT[tid + HALO - l];   // ca for rows 0..3 at this tap
        const long  o   = (long)l * LSTRIDE - l;
#pragma unroll
        for (int i = 0; i < ROWS; ++i)
            acc[i] = fmaf(xp[o + i * N], cav[i], acc[i]);
    }

    float* op = out + (long)m0 * NC + c;
#pragma unroll
    for (int i = 0; i < ROWS; ++i) op[i * NC] = acc[i];
}

extern "C" void kernel_launch(void* const* d_in, const int* in_sizes, int n_in,
                              void* d_out, int out_size, void* d_ws, size_t ws_size,
                              hipStream_t stream)
{
    const float* x  = (const float*)d_in[0];
    const float* ca = (const float*)d_in[1];
    float* out = (float*)d_out;

    dim3 block(BLK, 1, 1);
    dim3 grid((NC + BLK - 1) / BLK, M / ROWS, 1);   // (5, 256) = 1280 blocks
    cassi_fwd_kernel<<<grid, block, 0, stream>>>(x, ca, out);
}